// Round 1
// baseline (739.725 us; speedup 1.0000x reference)
//
#include <hip/hip_runtime.h>
#include <cstdint>
#include <cstddef>

// ---------- types ----------
typedef __attribute__((ext_vector_type(8)))  __bf16 bf16x8;
typedef __attribute__((ext_vector_type(4)))  float  f32x4;
typedef __attribute__((ext_vector_type(2)))  unsigned int u32x2;

#define DI __device__ __forceinline__

// ---------- problem constants ----------
constexpr int Cdim = 768;
constexpr int C3   = 2304;
constexpr int NT   = 65;                 // tokens per window (64 + unseen)
constexpr int ROWS = 1024 * NT;          // 66560
constexpr int ROWS_PAD = ROWS + 32;      // slack so padded frag loads stay in-buffer
constexpr int TP   = 96;                 // padded token dim for PV (3 x K32)
constexpr int PS   = 128;                // P LDS row stride in elems (256B, pow2 for XOR swizzle)
constexpr long long OUT_IMG = 16LL * 4096 * 768;  // 50331648 floats

DI float bf2f(unsigned short u) { unsigned int x = (unsigned int)u << 16; float f; __builtin_memcpy(&f, &x, 4); return f; }
DI unsigned short f2bf(float f) { unsigned int x; __builtin_memcpy(&x, &f, 4); x = x + 0x7fffu + ((x >> 16) & 1u); return (unsigned short)(x >> 16); }

DI void gload_lds16(const unsigned short* g, unsigned short* l) {
  __builtin_amdgcn_global_load_lds((__attribute__((address_space(1))) void*)g,
                                   (__attribute__((address_space(3))) void*)l, 16, 0, 0);
}

// ---------- K0: weights -> bf16, rope table ----------
__global__ void k_prep(const float* __restrict__ qkv_w, const float* __restrict__ proj_w,
                       unsigned short* __restrict__ wqb, unsigned short* __restrict__ wpb,
                       float* __restrict__ rope) {
  const int NW1 = 2304 * 768;   // 1769472
  const int NW2 = 768 * 768;    // 589824
  int total = NW1 + NW2 + 1024;
  for (int i = blockIdx.x * blockDim.x + threadIdx.x; i < total; i += gridDim.x * blockDim.x) {
    if (i < NW1) wqb[i] = f2bf(qkv_w[i]);
    else if (i < NW1 + NW2) wpb[i - NW1] = f2bf(proj_w[i - NW1]);
    else {
      int e = i - NW1 - NW2;            // e = p*16 + j, p in [0,64), j in [0,16)
      int p = e >> 4, j = e & 15;
      float inv = powf(100.f, -(float)j * (1.f / 16.f));   // 100^(-2j/32)
      float a = (float)p * inv;
      rope[2 * e]     = cosf(a);
      rope[2 * e + 1] = sinf(a);
    }
  }
}

// ---------- K1: window partition + unseen append -> bf16 xw [66560][768] ----------
__global__ void k_xw(const float* __restrict__ x, const float* __restrict__ unseen,
                     unsigned short* __restrict__ xw) {
  int row = blockIdx.x;                   // [0, 66560)
  int w = row / NT, t = row - w * NT;     // window, token
  const float* src;
  if (t == 64) {
    src = unseen + (size_t)(w >> 6) * Cdim;
  } else {
    int wy = (w >> 3) & 7, wx = w & 7;
    int hw = ((wy << 3) + (t >> 3)) * 64 + (wx << 3) + (t & 7);
    src = x + ((size_t)(w >> 6) * 4096 + hw) * Cdim;
  }
  float4 v = ((const float4*)src)[threadIdx.x];       // 192 threads * 4 = 768
  unsigned int u0 = (unsigned)f2bf(v.x) | ((unsigned)f2bf(v.y) << 16);
  unsigned int u1 = (unsigned)f2bf(v.z) | ((unsigned)f2bf(v.w) << 16);
  ((u32x2*)(xw + (size_t)row * Cdim))[threadIdx.x] = (u32x2){u0, u1};
}

// ---------- GEMM: C[M=66560, N] = A[M,768] @ Bw[N,768]^T + bias, m97-style 128^2 tile ----------
// MODE 0: out -> qkv bf16, fused RoPE on q/k image tokens.
// MODE 1: out -> fp32 d_out with window-merge scatter + unseen mean via atomicAdd.
template<int MODE, int NTILES>
__global__ __launch_bounds__(256) void k_gemm(
    const unsigned short* __restrict__ A, const unsigned short* __restrict__ Bw,
    const float* __restrict__ bias, const float* __restrict__ rope,
    unsigned short* __restrict__ Cb, float* __restrict__ outp) {
  constexpr int K = 768;
  __shared__ alignas(16) unsigned short As[128 * 64];
  __shared__ alignas(16) unsigned short Bs[128 * 64];

  constexpr int nwg = 520 * NTILES;          // % 8 == 0 -> simple bijective XCD swizzle
  int id = blockIdx.x;
  int wg = (id & 7) * (nwg >> 3) + (id >> 3);
  int mtile = wg / NTILES, ntile = wg - mtile * NTILES;
  int m0 = mtile * 128, n0 = ntile * 128;

  int tid = threadIdx.x;
  int lane = tid & 63, wid = tid >> 6;
  int lq = lane & 15, lg = lane >> 4;
  int wm = (wid >> 1) * 64, wn = (wid & 1) * 64;

  f32x4 acc[4][4];
  #pragma unroll
  for (int i = 0; i < 4; ++i)
    #pragma unroll
    for (int j = 0; j < 4; ++j) acc[i][j] = (f32x4){0.f, 0.f, 0.f, 0.f};

  for (int kt = 0; kt < K / 64; ++kt) {
    int k0 = kt * 64;
    // stage A/B tiles: 1024 16B-chunks each; LDS linear, global source pre-swizzled
    #pragma unroll
    for (int c = 0; c < 4; ++c) {
      int chunk = c * 256 + tid;
      int row = chunk >> 3, kc = chunk & 7;
      int skc = kc ^ (row & 7);
      gload_lds16(A + (size_t)(m0 + row) * K + k0 + skc * 8,
                  As + (size_t)(c * 256 + (tid & ~63)) * 8);
    }
    #pragma unroll
    for (int c = 0; c < 4; ++c) {
      int chunk = c * 256 + tid;
      int row = chunk >> 3, kc = chunk & 7;
      int skc = kc ^ (row & 7);
      gload_lds16(Bw + (size_t)(n0 + row) * K + k0 + skc * 8,
                  Bs + (size_t)(c * 256 + (tid & ~63)) * 8);
    }
    asm volatile("s_waitcnt vmcnt(0)" ::: "memory");
    __syncthreads();
    #pragma unroll
    for (int ks = 0; ks < 2; ++ks) {
      bf16x8 af[4], bfr[4];
      #pragma unroll
      for (int mt = 0; mt < 4; ++mt) {
        int row = wm + mt * 16 + lq;
        int ch = ((ks << 2) + lg) ^ (row & 7);
        af[mt] = *(const bf16x8*)(As + row * 64 + ch * 8);
      }
      #pragma unroll
      for (int nt = 0; nt < 4; ++nt) {
        int row = wn + nt * 16 + lq;
        int ch = ((ks << 2) + lg) ^ (row & 7);
        bfr[nt] = *(const bf16x8*)(Bs + row * 64 + ch * 8);
      }
      #pragma unroll
      for (int mt = 0; mt < 4; ++mt)
        #pragma unroll
        for (int nt = 0; nt < 4; ++nt)
          acc[mt][nt] = __builtin_amdgcn_mfma_f32_16x16x32_bf16(af[mt], bfr[nt], acc[mt][nt], 0, 0, 0);
    }
    __syncthreads();
  }

  // ---- epilogue ----
  #pragma unroll
  for (int mt = 0; mt < 4; ++mt) {
    #pragma unroll
    for (int r = 0; r < 4; ++r) {
      int row = m0 + wm + mt * 16 + (lg << 2) + r;      // global M row
      int w = row / NT, t = row - w * NT;
      int wy = (w >> 3) & 7, wx = w & 7;
      int py = (wy << 3) + (t >> 3), px = (wx << 3) + (t & 7);
      #pragma unroll
      for (int a = 0; a < 2; ++a) {                     // paired n-fragments (2a, 2a+1)
        int col0 = n0 + wn + a * 32 + lq;
        int col1 = col0 + 16;
        float v0 = acc[mt][2 * a][r] + bias[col0];
        float v1 = acc[mt][2 * a + 1][r] + bias[col1];
        if (MODE == 0) {
          if (col0 < 1536 && t != 64) {                 // RoPE on q/k image tokens
            int p = a ? px : py;                        // (col&63)>>5 == a
            const float* rp = rope + ((p << 4) + lq) * 2;
            float cc = rp[0], ss = rp[1];
            float o0 = v0 * cc - v1 * ss;
            float o1 = v1 * cc + v0 * ss;
            v0 = o0; v1 = o1;
          }
          unsigned short* cr = Cb + (size_t)row * C3;
          cr[col0] = f2bf(v0);
          cr[col1] = f2bf(v1);
        } else {
          if (t == 64) {
            float* ub = outp + OUT_IMG + (size_t)(w >> 6) * Cdim;
            atomicAdd(ub + col0, v0 * (1.f / 64.f));
            atomicAdd(ub + col1, v1 * (1.f / 64.f));
          } else {
            float* orow = outp + ((size_t)(w >> 6) * 4096 + py * 64 + px) * Cdim;
            orow[col0] = v0;
            orow[col1] = v1;
          }
        }
      }
    }
  }
}

// ---------- K3: V transpose per (window, head): Vt[bh][d][t], t padded to 96 with zeros ----------
__global__ void k_vt(const unsigned short* __restrict__ qkv, unsigned short* __restrict__ Vt) {
  int bh = blockIdx.x;                    // w*12 + h
  int w = bh / 12, h = bh - w * 12;
  __shared__ float sv[65][65];            // +1 pad col -> conflict-free transpose read
  const unsigned short* base = qkv + (size_t)w * NT * C3 + 1536 + h * 64;
  for (int i = threadIdx.x; i < 65 * 64; i += 256) {
    int t = i >> 6, d = i & 63;
    sv[t][d] = bf2f(base[(size_t)t * C3 + d]);
  }
  __syncthreads();
  unsigned short* out = Vt + (size_t)bh * 64 * TP;
  for (int i = threadIdx.x; i < 64 * TP; i += 256) {
    int d = i / TP, t = i - d * TP;
    out[i] = f2bf(t < 65 ? sv[t][d] : 0.f);
  }
}

// ---------- K4: attention, 1 wave per (window, head) ----------
// S^T = mfma(K, Q^T) -> softmax lane-local over tokens -> P via swizzled LDS -> O^T = mfma(V^T, P^T)
__global__ __launch_bounds__(64) void k_attn(const unsigned short* __restrict__ qkv,
                                             const unsigned short* __restrict__ Vt,
                                             unsigned short* __restrict__ att) {
  __shared__ alignas(16) unsigned short P[80 * PS];   // 20.5 KB, 256B row stride
  int h = blockIdx.x, w = blockIdx.y;
  int lane = threadIdx.x;
  int lq = lane & 15, lg = lane >> 4;

  const unsigned short* qb = qkv + (size_t)w * NT * C3 + h * 64;
  const unsigned short* kb = qb + 768;

  bf16x8 kf[5][2];
  #pragma unroll
  for (int kt = 0; kt < 5; ++kt)
    #pragma unroll
    for (int ks = 0; ks < 2; ++ks)
      kf[kt][ks] = *(const bf16x8*)(kb + (size_t)(kt * 16 + lq) * C3 + ks * 32 + lg * 8);

  const unsigned short* vb = Vt + (size_t)(w * 12 + h) * 64 * TP;
  bf16x8 vf[3][4];
  #pragma unroll
  for (int ks = 0; ks < 3; ++ks)
    #pragma unroll
    for (int dt = 0; dt < 4; ++dt)
      vf[ks][dt] = *(const bf16x8*)(vb + (size_t)(dt * 16 + lq) * TP + ks * 32 + lg * 8);

  // zero P columns 80..95 (swizzled addresses)
  for (int i = lane; i < 80 * 8; i += 64) {
    int row = i >> 3, j = i & 7;
    int byteo = row * (PS * 2) + 160 + j * 4;
    byteo ^= (row & 7) << 4;
    *(unsigned int*)((char*)P + byteo) = 0u;
  }

  #pragma unroll 1
  for (int qt = 0; qt < 5; ++qt) {
    bf16x8 qf[2];
    #pragma unroll
    for (int ks = 0; ks < 2; ++ks)
      qf[ks] = *(const bf16x8*)(qb + (size_t)(qt * 16 + lq) * C3 + ks * 32 + lg * 8);

    f32x4 sa[5];
    #pragma unroll
    for (int kt = 0; kt < 5; ++kt) {
      sa[kt] = (f32x4){0.f, 0.f, 0.f, 0.f};
      #pragma unroll
      for (int ks = 0; ks < 2; ++ks)
        sa[kt] = __builtin_amdgcn_mfma_f32_16x16x32_bf16(kf[kt][ks], qf[ks], sa[kt], 0, 0, 0);
    }
    // lane-local softmax for column q = qt*16+lq; token = kt*16 + lg*4 + r
    float pv[5][4];
    float m = -1e30f;
    #pragma unroll
    for (int kt = 0; kt < 5; ++kt)
      #pragma unroll
      for (int r = 0; r < 4; ++r) {
        int tok = kt * 16 + lg * 4 + r;
        float s = sa[kt][r] * 0.125f;
        bool ok = tok < 65;
        pv[kt][r] = ok ? s : -1e30f;
        m = (ok && s > m) ? s : m;
      }
    m = fmaxf(m, __shfl_xor(m, 16));
    m = fmaxf(m, __shfl_xor(m, 32));
    float sum = 0.f;
    #pragma unroll
    for (int kt = 0; kt < 5; ++kt)
      #pragma unroll
      for (int r = 0; r < 4; ++r) {
        float e = (pv[kt][r] > -1e29f) ? exp2f((pv[kt][r] - m) * 1.44269504f) : 0.f;
        pv[kt][r] = e;
        sum += e;
      }
    sum += __shfl_xor(sum, 16);
    sum += __shfl_xor(sum, 32);
    float rinv = 1.f / sum;

    int q = qt * 16 + lq;
    #pragma unroll
    for (int kt = 0; kt < 5; ++kt) {
      unsigned int u0 = (unsigned)f2bf(pv[kt][0] * rinv) | ((unsigned)f2bf(pv[kt][1] * rinv) << 16);
      unsigned int u1 = (unsigned)f2bf(pv[kt][2] * rinv) | ((unsigned)f2bf(pv[kt][3] * rinv) << 16);
      int byteo = q * (PS * 2) + kt * 32 + lg * 8;
      byteo ^= (q & 7) << 4;
      *(u32x2*)((char*)P + byteo) = (u32x2){u0, u1};
    }
    asm volatile("s_waitcnt lgkmcnt(0)" ::: "memory");

    bf16x8 bp[3];
    #pragma unroll
    for (int ks = 0; ks < 3; ++ks) {
      int byteo = q * (PS * 2) + ks * 64 + lg * 16;
      byteo ^= (q & 7) << 4;
      bp[ks] = *(const bf16x8*)((char*)P + byteo);
    }
    #pragma unroll
    for (int dt = 0; dt < 4; ++dt) {
      f32x4 o = (f32x4){0.f, 0.f, 0.f, 0.f};
      #pragma unroll
      for (int ks = 0; ks < 3; ++ks)
        o = __builtin_amdgcn_mfma_f32_16x16x32_bf16(vf[ks][dt], bp[ks], o, 0, 0, 0);
      if (q < 65) {
        unsigned int u0 = (unsigned)f2bf(o[0]) | ((unsigned)f2bf(o[1]) << 16);
        unsigned int u1 = (unsigned)f2bf(o[2]) | ((unsigned)f2bf(o[3]) << 16);
        *(u32x2*)(att + (size_t)(w * NT + q) * Cdim + h * 64 + dt * 16 + lg * 4) = (u32x2){u0, u1};
      }
    }
  }
}

// ---------- host ----------
extern "C" void kernel_launch(void* const* d_in, const int* in_sizes, int n_in,
                              void* d_out, int out_size, void* d_ws, size_t ws_size,
                              hipStream_t stream) {
  const float* x_img  = (const float*)d_in[0];
  // d_in[1] = pos2d_img: unused, positions derived analytically
  const float* unseen = (const float*)d_in[2];
  const float* qkv_w  = (const float*)d_in[3];
  const float* qkv_b  = (const float*)d_in[4];
  const float* proj_w = (const float*)d_in[5];
  const float* proj_b = (const float*)d_in[6];

  char* ws = (char*)d_ws;
  size_t off = 0;
  auto alloc = [&](size_t bytes) { void* p = ws + off; off = (off + bytes + 255) & ~(size_t)255; return p; };
  unsigned short* xw  = (unsigned short*)alloc((size_t)ROWS * Cdim * 2);       // reused as attn-out
  unsigned short* qkv = (unsigned short*)alloc((size_t)ROWS_PAD * C3 * 2);
  unsigned short* Vt  = (unsigned short*)alloc((size_t)12288 * 64 * TP * 2);
  unsigned short* wqb = (unsigned short*)alloc((size_t)C3 * Cdim * 2);
  unsigned short* wpb = (unsigned short*)alloc((size_t)Cdim * Cdim * 2);
  float* rope = (float*)alloc(64 * 16 * 2 * sizeof(float));
  // total ~539 MiB of d_ws

  // unseen-mean accumulator region must be zero each launch (atomicAdd target)
  hipMemsetAsync((float*)d_out + OUT_IMG, 0, 16 * Cdim * sizeof(float), stream);

  k_prep<<<512, 256, 0, stream>>>(qkv_w, proj_w, wqb, wpb, rope);
  k_xw<<<ROWS, 192, 0, stream>>>(x_img, unseen, xw);
  k_gemm<0, 18><<<520 * 18, 256, 0, stream>>>(xw, wqb, qkv_b, rope, qkv, nullptr);
  k_vt<<<12288, 256, 0, stream>>>(qkv, Vt);
  k_attn<<<dim3(12, 1024), 64, 0, stream>>>(qkv, Vt, xw);
  k_gemm<1, 6><<<520 * 6, 256, 0, stream>>>(xw, wpb, proj_b, nullptr, nullptr, (float*)d_out);
}

// Round 2
// 686.249 us; speedup vs baseline: 1.0779x; 1.0779x over previous
//
#include <hip/hip_runtime.h>
#include <cstdint>
#include <cstddef>

// ---------- types ----------
typedef __attribute__((ext_vector_type(8)))  __bf16 bf16x8;
typedef __attribute__((ext_vector_type(4)))  float  f32x4;
typedef __attribute__((ext_vector_type(2)))  unsigned int u32x2;

#define DI __device__ __forceinline__

// ---------- problem constants ----------
constexpr int Cdim = 768;
constexpr int C3   = 2304;
constexpr int NT   = 65;                 // tokens per window (64 + unseen)
constexpr int ROWS = 1024 * NT;          // 66560
constexpr int ROWS_PAD = ROWS + 32;
constexpr int TP   = 96;                 // padded token dim for PV (3 x K32)
constexpr int PS   = 128;                // P LDS row stride in elems
constexpr long long OUT_IMG = 16LL * 4096 * 768;  // 50331648 floats

DI float bf2f(unsigned short u) { unsigned int x = (unsigned int)u << 16; float f; __builtin_memcpy(&f, &x, 4); return f; }
DI unsigned short f2bf(float f) { unsigned int x; __builtin_memcpy(&x, &f, 4); x = x + 0x7fffu + ((x >> 16) & 1u); return (unsigned short)(x >> 16); }

DI void gload_lds16(const unsigned short* g, unsigned short* l) {
  __builtin_amdgcn_global_load_lds((__attribute__((address_space(1))) void*)g,
                                   (__attribute__((address_space(3))) void*)l, 16, 0, 0);
}

// ---------- K0: weights -> bf16, rope table ----------
__global__ void k_prep(const float* __restrict__ qkv_w, const float* __restrict__ proj_w,
                       unsigned short* __restrict__ wqb, unsigned short* __restrict__ wpb,
                       float* __restrict__ rope) {
  const int NW1 = 2304 * 768;
  const int NW2 = 768 * 768;
  int total = NW1 + NW2 + 1024;
  for (int i = blockIdx.x * blockDim.x + threadIdx.x; i < total; i += gridDim.x * blockDim.x) {
    if (i < NW1) wqb[i] = f2bf(qkv_w[i]);
    else if (i < NW1 + NW2) wpb[i - NW1] = f2bf(proj_w[i - NW1]);
    else {
      int e = i - NW1 - NW2;            // e = p*16 + j
      int p = e >> 4, j = e & 15;
      float inv = powf(100.f, -(float)j * (1.f / 16.f));
      float a = (float)p * inv;
      rope[2 * e]     = cosf(a);
      rope[2 * e + 1] = sinf(a);
    }
  }
}

// ---------- K1: window partition + unseen append -> bf16 xw [66560][768] ----------
__global__ void k_xw(const float* __restrict__ x, const float* __restrict__ unseen,
                     unsigned short* __restrict__ xw) {
  int row = blockIdx.x;
  int w = row / NT, t = row - w * NT;
  const float* src;
  if (t == 64) {
    src = unseen + (size_t)(w >> 6) * Cdim;
  } else {
    int wy = (w >> 3) & 7, wx = w & 7;
    int hw = ((wy << 3) + (t >> 3)) * 64 + (wx << 3) + (t & 7);
    src = x + ((size_t)(w >> 6) * 4096 + hw) * Cdim;
  }
  float4 v = ((const float4*)src)[threadIdx.x];
  unsigned int u0 = (unsigned)f2bf(v.x) | ((unsigned)f2bf(v.y) << 16);
  unsigned int u1 = (unsigned)f2bf(v.z) | ((unsigned)f2bf(v.w) << 16);
  ((u32x2*)(xw + (size_t)row * Cdim))[threadIdx.x] = (u32x2){u0, u1};
}

// ---------- GEMM: C[M=66560, N] = A[M,768] @ Bw[N,768]^T + bias ----------
// 256x256 tile, BK=32, 8 waves (2Mx4N, per-wave 128x64), 4 LDS buffers,
// 3-tile prefetch lookahead, counted vmcnt(8) + raw s_barrier per K-tile.
// MODE 0: out -> qkv bf16, fused RoPE.  MODE 1: out -> fp32 scatter + unseen mean.
template<int MODE, int NTILES>
__global__ __launch_bounds__(512, 2) void k_gemm(
    const unsigned short* __restrict__ A, const unsigned short* __restrict__ Bw,
    const float* __restrict__ bias, const float* __restrict__ rope,
    unsigned short* __restrict__ Cb, float* __restrict__ outp) {
  constexpr int K = 768;
  constexpr int NK = K / 32;             // 24 K-tiles
  constexpr int BUF = 16384;             // elems per buffer (A 8192 + B 8192)
  __shared__ alignas(16) unsigned short lds[4 * BUF];   // 128 KiB

  // bijective XCD swizzle (nwg may not be %8)
  constexpr int nwg = 260 * NTILES;
  constexpr int q8 = nwg / 8, r8 = nwg % 8;
  int id = blockIdx.x;
  int xcd = id & 7, lid = id >> 3;
  int wg = (xcd < r8 ? xcd * (q8 + 1) : r8 * (q8 + 1) + (xcd - r8) * q8) + lid;
  int mtile = wg / NTILES, ntile = wg - mtile * NTILES;
  int m0 = mtile * 256, n0 = ntile * 256;

  int tid = threadIdx.x;
  int lane = tid & 63, wid = tid >> 6;
  int lq = lane & 15, lg = lane >> 4;
  int wm = (wid >> 2) * 128;             // wave M offset (0 or 128)
  int wn = (wid & 3) * 64;               // wave N offset (0..192)

  // stage helpers: linear LDS, linear global (contiguous frag reads are bank-optimal at BK=32)
  auto stageA = [&](int tt) {
    unsigned short* d = lds + (tt & 3) * BUF;
    int k0 = tt * 32;
    #pragma unroll
    for (int c = 0; c < 2; ++c) {
      int chunk = c * 512 + tid;
      gload_lds16(A + (size_t)(m0 + (chunk >> 2)) * K + k0 + (chunk & 3) * 8,
                  d + (size_t)(c * 512 + (tid & ~63)) * 8);
    }
  };
  auto stageB = [&](int tt) {
    unsigned short* d = lds + (tt & 3) * BUF + 8192;
    int k0 = tt * 32;
    #pragma unroll
    for (int c = 0; c < 2; ++c) {
      int chunk = c * 512 + tid;
      gload_lds16(Bw + (size_t)(n0 + (chunk >> 2)) * K + k0 + (chunk & 3) * 8,
                  d + (size_t)(c * 512 + (tid & ~63)) * 8);
    }
  };

  f32x4 acc[8][4];
  #pragma unroll
  for (int i = 0; i < 8; ++i)
    #pragma unroll
    for (int j = 0; j < 4; ++j) acc[i][j] = (f32x4){0.f, 0.f, 0.f, 0.f};

  // prologue: stage tiles 0,1,2 (12 loads); wait oldest 4 (tile 0) -> vmcnt(8)
  stageA(0); stageB(0);
  stageA(1); stageB(1);
  stageA(2); stageB(2);
  asm volatile("s_waitcnt vmcnt(8)\n\ts_barrier" ::: "memory");

  for (int t = 0; t < NK; ++t) {
    const unsigned short* sA = lds + (t & 3) * BUF;
    const unsigned short* sB = sA + 8192;
    int tp = t + 3;

    // ---- phase 0: B frags (all 4) + A frags 0-3; stage A(t+3); 16 MFMA ----
    bf16x8 bfr[4], af[4];
    #pragma unroll
    for (int nf = 0; nf < 4; ++nf)
      bfr[nf] = *(const bf16x8*)(sB + (wn + nf * 16 + lq) * 32 + lg * 8);
    #pragma unroll
    for (int mf = 0; mf < 4; ++mf)
      af[mf] = *(const bf16x8*)(sA + (wm + mf * 16 + lq) * 32 + lg * 8);
    if (tp < NK) stageA(tp);
    __builtin_amdgcn_s_setprio(1);
    #pragma unroll
    for (int mf = 0; mf < 4; ++mf)
      #pragma unroll
      for (int nf = 0; nf < 4; ++nf)
        acc[mf][nf] = __builtin_amdgcn_mfma_f32_16x16x32_bf16(af[mf], bfr[nf], acc[mf][nf], 0, 0, 0);
    __builtin_amdgcn_s_setprio(0);

    // ---- phase 1: A frags 4-7; stage B(t+3); 16 MFMA ----
    bf16x8 af2[4];
    #pragma unroll
    for (int mf = 0; mf < 4; ++mf)
      af2[mf] = *(const bf16x8*)(sA + (wm + 64 + mf * 16 + lq) * 32 + lg * 8);
    if (tp < NK) stageB(tp);
    __builtin_amdgcn_s_setprio(1);
    #pragma unroll
    for (int mf = 0; mf < 4; ++mf)
      #pragma unroll
      for (int nf = 0; nf < 4; ++nf)
        acc[4 + mf][nf] = __builtin_amdgcn_mfma_f32_16x16x32_bf16(af2[mf], bfr[nf], acc[4 + mf][nf], 0, 0, 0);
    __builtin_amdgcn_s_setprio(0);

    // ---- tile end: counted wait guarantees tile t+1 staged; keep rest in flight ----
    if (t < NK - 1) {
      if (t <= NK - 4)      asm volatile("s_waitcnt vmcnt(8)\n\ts_barrier" ::: "memory");
      else if (t == NK - 3) asm volatile("s_waitcnt vmcnt(4)\n\ts_barrier" ::: "memory");
      else                  asm volatile("s_waitcnt vmcnt(0)\n\ts_barrier" ::: "memory");
    }
  }

  // ---- epilogue ----
  #pragma unroll
  for (int mf = 0; mf < 8; ++mf) {
    #pragma unroll
    for (int r = 0; r < 4; ++r) {
      int row = m0 + wm + mf * 16 + (lg << 2) + r;
      int w = row / NT, t = row - w * NT;
      int wy = (w >> 3) & 7, wx = w & 7;
      int py = (wy << 3) + (t >> 3), px = (wx << 3) + (t & 7);
      #pragma unroll
      for (int a = 0; a < 2; ++a) {
        int col0 = n0 + wn + a * 32 + lq;
        int col1 = col0 + 16;
        float v0 = acc[mf][2 * a][r] + bias[col0];
        float v1 = acc[mf][2 * a + 1][r] + bias[col1];
        if (MODE == 0) {
          if (col0 < 1536 && t != 64) {
            int p = a ? px : py;                 // (col0 & 63) >> 5 == a
            const float* rp = rope + ((p << 4) + lq) * 2;
            float cc = rp[0], ss = rp[1];
            float o0 = v0 * cc - v1 * ss;
            float o1 = v1 * cc + v0 * ss;
            v0 = o0; v1 = o1;
          }
          unsigned short* cr = Cb + (size_t)row * C3;
          cr[col0] = f2bf(v0);
          cr[col1] = f2bf(v1);
        } else {
          if (t == 64) {
            float* ub = outp + OUT_IMG + (size_t)(w >> 6) * Cdim;
            atomicAdd(ub + col0, v0 * (1.f / 64.f));
            atomicAdd(ub + col1, v1 * (1.f / 64.f));
          } else {
            float* orow = outp + ((size_t)(w >> 6) * 4096 + py * 64 + px) * Cdim;
            orow[col0] = v0;
            orow[col1] = v1;
          }
        }
      }
    }
  }
}

// ---------- K3: V transpose per (window, head) ----------
__global__ void k_vt(const unsigned short* __restrict__ qkv, unsigned short* __restrict__ Vt) {
  int bh = blockIdx.x;
  int w = bh / 12, h = bh - w * 12;
  __shared__ float sv[65][65];
  const unsigned short* base = qkv + (size_t)w * NT * C3 + 1536 + h * 64;
  for (int i = threadIdx.x; i < 65 * 64; i += 256) {
    int t = i >> 6, d = i & 63;
    sv[t][d] = bf2f(base[(size_t)t * C3 + d]);
  }
  __syncthreads();
  unsigned short* out = Vt + (size_t)bh * 64 * TP;
  for (int i = threadIdx.x; i < 64 * TP; i += 256) {
    int d = i / TP, t = i - d * TP;
    out[i] = f2bf(t < 65 ? sv[t][d] : 0.f);
  }
}

// ---------- K4: attention, 1 wave per (window, head) ----------
__global__ __launch_bounds__(64) void k_attn(const unsigned short* __restrict__ qkv,
                                             const unsigned short* __restrict__ Vt,
                                             unsigned short* __restrict__ att) {
  __shared__ alignas(16) unsigned short P[80 * PS];
  int h = blockIdx.x, w = blockIdx.y;
  int lane = threadIdx.x;
  int lq = lane & 15, lg = lane >> 4;

  const unsigned short* qb = qkv + (size_t)w * NT * C3 + h * 64;
  const unsigned short* kb = qb + 768;

  bf16x8 kf[5][2];
  #pragma unroll
  for (int kt = 0; kt < 5; ++kt)
    #pragma unroll
    for (int ks = 0; ks < 2; ++ks)
      kf[kt][ks] = *(const bf16x8*)(kb + (size_t)(kt * 16 + lq) * C3 + ks * 32 + lg * 8);

  const unsigned short* vb = Vt + (size_t)(w * 12 + h) * 64 * TP;
  bf16x8 vf[3][4];
  #pragma unroll
  for (int ks = 0; ks < 3; ++ks)
    #pragma unroll
    for (int dt = 0; dt < 4; ++dt)
      vf[ks][dt] = *(const bf16x8*)(vb + (size_t)(dt * 16 + lq) * TP + ks * 32 + lg * 8);

  for (int i = lane; i < 80 * 8; i += 64) {
    int row = i >> 3, j = i & 7;
    int byteo = row * (PS * 2) + 160 + j * 4;
    byteo ^= (row & 7) << 4;
    *(unsigned int*)((char*)P + byteo) = 0u;
  }

  #pragma unroll 1
  for (int qt = 0; qt < 5; ++qt) {
    bf16x8 qf[2];
    #pragma unroll
    for (int ks = 0; ks < 2; ++ks)
      qf[ks] = *(const bf16x8*)(qb + (size_t)(qt * 16 + lq) * C3 + ks * 32 + lg * 8);

    f32x4 sa[5];
    #pragma unroll
    for (int kt = 0; kt < 5; ++kt) {
      sa[kt] = (f32x4){0.f, 0.f, 0.f, 0.f};
      #pragma unroll
      for (int ks = 0; ks < 2; ++ks)
        sa[kt] = __builtin_amdgcn_mfma_f32_16x16x32_bf16(kf[kt][ks], qf[ks], sa[kt], 0, 0, 0);
    }
    float pv[5][4];
    float m = -1e30f;
    #pragma unroll
    for (int kt = 0; kt < 5; ++kt)
      #pragma unroll
      for (int r = 0; r < 4; ++r) {
        int tok = kt * 16 + lg * 4 + r;
        float s = sa[kt][r] * 0.125f;
        bool ok = tok < 65;
        pv[kt][r] = ok ? s : -1e30f;
        m = (ok && s > m) ? s : m;
      }
    m = fmaxf(m, __shfl_xor(m, 16));
    m = fmaxf(m, __shfl_xor(m, 32));
    float sum = 0.f;
    #pragma unroll
    for (int kt = 0; kt < 5; ++kt)
      #pragma unroll
      for (int r = 0; r < 4; ++r) {
        float e = (pv[kt][r] > -1e29f) ? exp2f((pv[kt][r] - m) * 1.44269504f) : 0.f;
        pv[kt][r] = e;
        sum += e;
      }
    sum += __shfl_xor(sum, 16);
    sum += __shfl_xor(sum, 32);
    float rinv = 1.f / sum;

    int q = qt * 16 + lq;
    #pragma unroll
    for (int kt = 0; kt < 5; ++kt) {
      unsigned int u0 = (unsigned)f2bf(pv[kt][0] * rinv) | ((unsigned)f2bf(pv[kt][1] * rinv) << 16);
      unsigned int u1 = (unsigned)f2bf(pv[kt][2] * rinv) | ((unsigned)f2bf(pv[kt][3] * rinv) << 16);
      int byteo = q * (PS * 2) + kt * 32 + lg * 8;
      byteo ^= (q & 7) << 4;
      *(u32x2*)((char*)P + byteo) = (u32x2){u0, u1};
    }
    asm volatile("s_waitcnt lgkmcnt(0)" ::: "memory");

    bf16x8 bp[3];
    #pragma unroll
    for (int ks = 0; ks < 3; ++ks) {
      int byteo = q * (PS * 2) + ks * 64 + lg * 16;
      byteo ^= (q & 7) << 4;
      bp[ks] = *(const bf16x8*)((char*)P + byteo);
    }
    #pragma unroll
    for (int dt = 0; dt < 4; ++dt) {
      f32x4 o = (f32x4){0.f, 0.f, 0.f, 0.f};
      #pragma unroll
      for (int ks = 0; ks < 3; ++ks)
        o = __builtin_amdgcn_mfma_f32_16x16x32_bf16(vf[ks][dt], bp[ks], o, 0, 0, 0);
      if (q < 65) {
        unsigned int u0 = (unsigned)f2bf(o[0]) | ((unsigned)f2bf(o[1]) << 16);
        unsigned int u1 = (unsigned)f2bf(o[2]) | ((unsigned)f2bf(o[3]) << 16);
        *(u32x2*)(att + (size_t)(w * NT + q) * Cdim + h * 64 + dt * 16 + lg * 4) = (u32x2){u0, u1};
      }
    }
  }
}

// ---------- host ----------
extern "C" void kernel_launch(void* const* d_in, const int* in_sizes, int n_in,
                              void* d_out, int out_size, void* d_ws, size_t ws_size,
                              hipStream_t stream) {
  const float* x_img  = (const float*)d_in[0];
  const float* unseen = (const float*)d_in[2];
  const float* qkv_w  = (const float*)d_in[3];
  const float* qkv_b  = (const float*)d_in[4];
  const float* proj_w = (const float*)d_in[5];
  const float* proj_b = (const float*)d_in[6];

  char* ws = (char*)d_ws;
  size_t off = 0;
  auto alloc = [&](size_t bytes) { void* p = ws + off; off = (off + bytes + 255) & ~(size_t)255; return p; };
  unsigned short* xw  = (unsigned short*)alloc((size_t)ROWS * Cdim * 2);
  unsigned short* qkv = (unsigned short*)alloc((size_t)ROWS_PAD * C3 * 2);
  unsigned short* Vt  = (unsigned short*)alloc((size_t)12288 * 64 * TP * 2);
  unsigned short* wqb = (unsigned short*)alloc((size_t)C3 * Cdim * 2);
  unsigned short* wpb = (unsigned short*)alloc((size_t)Cdim * Cdim * 2);
  float* rope = (float*)alloc(64 * 16 * 2 * sizeof(float));

  hipMemsetAsync((float*)d_out + OUT_IMG, 0, 16 * Cdim * sizeof(float), stream);

  k_prep<<<512, 256, 0, stream>>>(qkv_w, proj_w, wqb, wpb, rope);
  k_xw<<<ROWS, 192, 0, stream>>>(x_img, unseen, xw);
  k_gemm<0, 9><<<260 * 9, 512, 0, stream>>>(xw, wqb, qkv_b, rope, qkv, nullptr);
  k_vt<<<12288, 256, 0, stream>>>(qkv, Vt);
  k_attn<<<dim3(12, 1024), 64, 0, stream>>>(qkv, Vt, xw);
  k_gemm<1, 3><<<260 * 3, 512, 0, stream>>>(xw, wpb, proj_b, nullptr, nullptr, (float*)d_out);
}

// Round 3
// 678.026 us; speedup vs baseline: 1.0910x; 1.0121x over previous
//
#include <hip/hip_runtime.h>
#include <cstdint>
#include <cstddef>

// ---------- types ----------
typedef __attribute__((ext_vector_type(8)))  __bf16 bf16x8;
typedef __attribute__((ext_vector_type(4)))  float  f32x4;
typedef __attribute__((ext_vector_type(2)))  unsigned int u32x2;

#define DI __device__ __forceinline__

// ---------- problem constants ----------
constexpr int Cdim = 768;
constexpr int C3   = 2304;
constexpr int NT   = 65;                 // tokens per window (64 + unseen)
constexpr int ROWS = 1024 * NT;          // 66560
constexpr int ROWS_PAD = ROWS + 32;
constexpr int TP   = 96;                 // padded token dim for PV (3 x K32)
constexpr int PS   = 128;                // P LDS row stride in elems
constexpr long long OUT_IMG = 16LL * 4096 * 768;  // 50331648 floats

DI float bf2f(unsigned short u) { unsigned int x = (unsigned int)u << 16; float f; __builtin_memcpy(&f, &x, 4); return f; }
DI unsigned short f2bf(float f) { unsigned int x; __builtin_memcpy(&x, &f, 4); x = x + 0x7fffu + ((x >> 16) & 1u); return (unsigned short)(x >> 16); }

DI void gload_lds16(const unsigned short* g, unsigned short* l) {
  __builtin_amdgcn_global_load_lds((__attribute__((address_space(1))) void*)g,
                                   (__attribute__((address_space(3))) void*)l, 16, 0, 0);
}

// ---------- K0: weights -> bf16, rope table ----------
__global__ void k_prep(const float* __restrict__ qkv_w, const float* __restrict__ proj_w,
                       unsigned short* __restrict__ wqb, unsigned short* __restrict__ wpb,
                       float* __restrict__ rope) {
  const int NW1 = 2304 * 768;
  const int NW2 = 768 * 768;
  int total = NW1 + NW2 + 1024;
  for (int i = blockIdx.x * blockDim.x + threadIdx.x; i < total; i += gridDim.x * blockDim.x) {
    if (i < NW1) wqb[i] = f2bf(qkv_w[i]);
    else if (i < NW1 + NW2) wpb[i - NW1] = f2bf(proj_w[i - NW1]);
    else {
      int e = i - NW1 - NW2;            // e = p*16 + j
      int p = e >> 4, j = e & 15;
      float inv = powf(100.f, -(float)j * (1.f / 16.f));
      float a = (float)p * inv;
      rope[2 * e]     = cosf(a);
      rope[2 * e + 1] = sinf(a);
    }
  }
}

// ---------- K1: window partition + unseen append -> bf16 xw [66560][768] ----------
__global__ void k_xw(const float* __restrict__ x, const float* __restrict__ unseen,
                     unsigned short* __restrict__ xw) {
  int row = blockIdx.x;
  int w = row / NT, t = row - w * NT;
  const float* src;
  if (t == 64) {
    src = unseen + (size_t)(w >> 6) * Cdim;
  } else {
    int wy = (w >> 3) & 7, wx = w & 7;
    int hw = ((wy << 3) + (t >> 3)) * 64 + (wx << 3) + (t & 7);
    src = x + ((size_t)(w >> 6) * 4096 + hw) * Cdim;
  }
  float4 v = ((const float4*)src)[threadIdx.x];
  unsigned int u0 = (unsigned)f2bf(v.x) | ((unsigned)f2bf(v.y) << 16);
  unsigned int u1 = (unsigned)f2bf(v.z) | ((unsigned)f2bf(v.w) << 16);
  ((u32x2*)(xw + (size_t)row * Cdim))[threadIdx.x] = (u32x2){u0, u1};
}

// ---------- GEMM: C[M=66560, N] = A[M,768] @ Bw[N,768]^T + bias ----------
// 256x256 tile, BK=32, 8 waves (2Mx4N, per-wave 128x64), 4 LDS buffers,
// 3-tile prefetch lookahead, counted vmcnt(8) + raw s_barrier per K-tile.
// BOTH-SIDES XOR swizzle (chunk ^= (row>>1)&3): 2-way bank aliasing (free)
// on ds_read_b128 frag reads; linear LDS dest for global_load_lds with
// pre-swizzled global source (involution on byte bits 4-5 keyed by 7-8).
// MODE 0: out -> qkv bf16, fused RoPE.  MODE 1: out -> fp32 scatter + unseen mean.
template<int MODE, int NTILES>
__global__ __launch_bounds__(512, 2) void k_gemm(
    const unsigned short* __restrict__ A, const unsigned short* __restrict__ Bw,
    const float* __restrict__ bias, const float* __restrict__ rope,
    unsigned short* __restrict__ Cb, float* __restrict__ outp) {
  constexpr int K = 768;
  constexpr int NK = K / 32;             // 24 K-tiles
  constexpr int BUF = 16384;             // elems per buffer (A 8192 + B 8192)
  __shared__ alignas(16) unsigned short lds[4 * BUF];   // 128 KiB

  // bijective XCD swizzle
  constexpr int nwg = 260 * NTILES;
  constexpr int q8 = nwg / 8, r8 = nwg % 8;
  int id = blockIdx.x;
  int xcd = id & 7, lid = id >> 3;
  int wg = (xcd < r8 ? xcd * (q8 + 1) : r8 * (q8 + 1) + (xcd - r8) * q8) + lid;
  int mtile = wg / NTILES, ntile = wg - mtile * NTILES;
  int m0 = mtile * 256, n0 = ntile * 256;

  int tid = threadIdx.x;
  int lane = tid & 63, wid = tid >> 6;
  int lq = lane & 15, lg = lane >> 4;
  int wm = (wid >> 2) * 128;             // wave M offset (0 or 128)
  int wn = (wid & 3) * 64;               // wave N offset (0..192)

  // stage helpers: linear LDS dest, pre-swizzled global source
  auto stageA = [&](int tt) {
    unsigned short* d = lds + (tt & 3) * BUF;
    int k0 = tt * 32;
    #pragma unroll
    for (int c = 0; c < 2; ++c) {
      int ch = c * 512 + tid;
      int row = ch >> 2, kc = ch & 3;
      int skc = kc ^ ((row >> 1) & 3);
      gload_lds16(A + (size_t)(m0 + row) * K + k0 + skc * 8,
                  d + (size_t)(c * 512 + (tid & ~63)) * 8);
    }
  };
  auto stageB = [&](int tt) {
    unsigned short* d = lds + (tt & 3) * BUF + 8192;
    int k0 = tt * 32;
    #pragma unroll
    for (int c = 0; c < 2; ++c) {
      int ch = c * 512 + tid;
      int row = ch >> 2, kc = ch & 3;
      int skc = kc ^ ((row >> 1) & 3);
      gload_lds16(Bw + (size_t)(n0 + row) * K + k0 + skc * 8,
                  d + (size_t)(c * 512 + (tid & ~63)) * 8);
    }
  };

  f32x4 acc[8][4];
  #pragma unroll
  for (int i = 0; i < 8; ++i)
    #pragma unroll
    for (int j = 0; j < 4; ++j) acc[i][j] = (f32x4){0.f, 0.f, 0.f, 0.f};

  // prologue: stage tiles 0,1,2 (12 loads); wait oldest 4 (tile 0) -> vmcnt(8)
  stageA(0); stageB(0);
  stageA(1); stageB(1);
  stageA(2); stageB(2);
  asm volatile("s_waitcnt vmcnt(8)\n\ts_barrier" ::: "memory");

  for (int t = 0; t < NK; ++t) {
    const unsigned short* sA = lds + (t & 3) * BUF;
    const unsigned short* sB = sA + 8192;
    int tp = t + 3;

    // ---- phase 0: B frags (all 4) + A frags 0-3 (swizzled reads); stage A(t+3); 16 MFMA ----
    bf16x8 bfr[4], af[4];
    #pragma unroll
    for (int nf = 0; nf < 4; ++nf) {
      int row = wn + nf * 16 + lq;
      bfr[nf] = *(const bf16x8*)(sB + row * 32 + (lg ^ ((row >> 1) & 3)) * 8);
    }
    #pragma unroll
    for (int mf = 0; mf < 4; ++mf) {
      int row = wm + mf * 16 + lq;
      af[mf] = *(const bf16x8*)(sA + row * 32 + (lg ^ ((row >> 1) & 3)) * 8);
    }
    if (tp < NK) stageA(tp);
    __builtin_amdgcn_s_setprio(1);
    #pragma unroll
    for (int mf = 0; mf < 4; ++mf)
      #pragma unroll
      for (int nf = 0; nf < 4; ++nf)
        acc[mf][nf] = __builtin_amdgcn_mfma_f32_16x16x32_bf16(af[mf], bfr[nf], acc[mf][nf], 0, 0, 0);
    __builtin_amdgcn_s_setprio(0);

    // ---- phase 1: A frags 4-7; stage B(t+3); 16 MFMA ----
    bf16x8 af2[4];
    #pragma unroll
    for (int mf = 0; mf < 4; ++mf) {
      int row = wm + 64 + mf * 16 + lq;
      af2[mf] = *(const bf16x8*)(sA + row * 32 + (lg ^ ((row >> 1) & 3)) * 8);
    }
    if (tp < NK) stageB(tp);
    __builtin_amdgcn_s_setprio(1);
    #pragma unroll
    for (int mf = 0; mf < 4; ++mf)
      #pragma unroll
      for (int nf = 0; nf < 4; ++nf)
        acc[4 + mf][nf] = __builtin_amdgcn_mfma_f32_16x16x32_bf16(af2[mf], bfr[nf], acc[4 + mf][nf], 0, 0, 0);
    __builtin_amdgcn_s_setprio(0);

    // ---- tile end: counted wait guarantees tile t+1 staged; keep rest in flight ----
    if (t < NK - 1) {
      if (t <= NK - 4)      asm volatile("s_waitcnt vmcnt(8)\n\ts_barrier" ::: "memory");
      else if (t == NK - 3) asm volatile("s_waitcnt vmcnt(4)\n\ts_barrier" ::: "memory");
      else                  asm volatile("s_waitcnt vmcnt(0)\n\ts_barrier" ::: "memory");
    }
  }

  // ---- epilogue ----
  #pragma unroll
  for (int mf = 0; mf < 8; ++mf) {
    #pragma unroll
    for (int r = 0; r < 4; ++r) {
      int row = m0 + wm + mf * 16 + (lg << 2) + r;
      int w = row / NT, t = row - w * NT;
      int wy = (w >> 3) & 7, wx = w & 7;
      int py = (wy << 3) + (t >> 3), px = (wx << 3) + (t & 7);
      #pragma unroll
      for (int a = 0; a < 2; ++a) {
        int col0 = n0 + wn + a * 32 + lq;
        int col1 = col0 + 16;
        float v0 = acc[mf][2 * a][r] + bias[col0];
        float v1 = acc[mf][2 * a + 1][r] + bias[col1];
        if (MODE == 0) {
          if (col0 < 1536 && t != 64) {
            int p = a ? px : py;                 // (col0 & 63) >> 5 == a
            const float* rp = rope + ((p << 4) + lq) * 2;
            float cc = rp[0], ss = rp[1];
            float o0 = v0 * cc - v1 * ss;
            float o1 = v1 * cc + v0 * ss;
            v0 = o0; v1 = o1;
          }
          unsigned short* cr = Cb + (size_t)row * C3;
          cr[col0] = f2bf(v0);
          cr[col1] = f2bf(v1);
        } else {
          if (t == 64) {
            float* ub = outp + OUT_IMG + (size_t)(w >> 6) * Cdim;
            atomicAdd(ub + col0, v0 * (1.f / 64.f));
            atomicAdd(ub + col1, v1 * (1.f / 64.f));
          } else {
            float* orow = outp + ((size_t)(w >> 6) * 4096 + py * 64 + px) * Cdim;
            orow[col0] = v0;
            orow[col1] = v1;
          }
        }
      }
    }
  }
}

// ---------- K3: V transpose per (window, head) ----------
__global__ void k_vt(const unsigned short* __restrict__ qkv, unsigned short* __restrict__ Vt) {
  int bh = blockIdx.x;
  int w = bh / 12, h = bh - w * 12;
  __shared__ float sv[65][65];
  const unsigned short* base = qkv + (size_t)w * NT * C3 + 1536 + h * 64;
  for (int i = threadIdx.x; i < 65 * 64; i += 256) {
    int t = i >> 6, d = i & 63;
    sv[t][d] = bf2f(base[(size_t)t * C3 + d]);
  }
  __syncthreads();
  unsigned short* out = Vt + (size_t)bh * 64 * TP;
  for (int i = threadIdx.x; i < 64 * TP; i += 256) {
    int d = i / TP, t = i - d * TP;
    out[i] = f2bf(t < 65 ? sv[t][d] : 0.f);
  }
}

// ---------- K4: attention, 1 wave per (window, head) ----------
__global__ __launch_bounds__(64) void k_attn(const unsigned short* __restrict__ qkv,
                                             const unsigned short* __restrict__ Vt,
                                             unsigned short* __restrict__ att) {
  __shared__ alignas(16) unsigned short P[80 * PS];
  int h = blockIdx.x, w = blockIdx.y;
  int lane = threadIdx.x;
  int lq = lane & 15, lg = lane >> 4;

  const unsigned short* qb = qkv + (size_t)w * NT * C3 + h * 64;
  const unsigned short* kb = qb + 768;

  bf16x8 kf[5][2];
  #pragma unroll
  for (int kt = 0; kt < 5; ++kt)
    #pragma unroll
    for (int ks = 0; ks < 2; ++ks)
      kf[kt][ks] = *(const bf16x8*)(kb + (size_t)(kt * 16 + lq) * C3 + ks * 32 + lg * 8);

  const unsigned short* vb = Vt + (size_t)(w * 12 + h) * 64 * TP;
  bf16x8 vf[3][4];
  #pragma unroll
  for (int ks = 0; ks < 3; ++ks)
    #pragma unroll
    for (int dt = 0; dt < 4; ++dt)
      vf[ks][dt] = *(const bf16x8*)(vb + (size_t)(dt * 16 + lq) * TP + ks * 32 + lg * 8);

  for (int i = lane; i < 80 * 8; i += 64) {
    int row = i >> 3, j = i & 7;
    int byteo = row * (PS * 2) + 160 + j * 4;
    byteo ^= (row & 7) << 4;
    *(unsigned int*)((char*)P + byteo) = 0u;
  }

  #pragma unroll 1
  for (int qt = 0; qt < 5; ++qt) {
    bf16x8 qf[2];
    #pragma unroll
    for (int ks = 0; ks < 2; ++ks)
      qf[ks] = *(const bf16x8*)(qb + (size_t)(qt * 16 + lq) * C3 + ks * 32 + lg * 8);

    f32x4 sa[5];
    #pragma unroll
    for (int kt = 0; kt < 5; ++kt) {
      sa[kt] = (f32x4){0.f, 0.f, 0.f, 0.f};
      #pragma unroll
      for (int ks = 0; ks < 2; ++ks)
        sa[kt] = __builtin_amdgcn_mfma_f32_16x16x32_bf16(kf[kt][ks], qf[ks], sa[kt], 0, 0, 0);
    }
    float pv[5][4];
    float m = -1e30f;
    #pragma unroll
    for (int kt = 0; kt < 5; ++kt)
      #pragma unroll
      for (int r = 0; r < 4; ++r) {
        int tok = kt * 16 + lg * 4 + r;
        float s = sa[kt][r] * 0.125f;
        bool ok = tok < 65;
        pv[kt][r] = ok ? s : -1e30f;
        m = (ok && s > m) ? s : m;
      }
    m = fmaxf(m, __shfl_xor(m, 16));
    m = fmaxf(m, __shfl_xor(m, 32));
    float sum = 0.f;
    #pragma unroll
    for (int kt = 0; kt < 5; ++kt)
      #pragma unroll
      for (int r = 0; r < 4; ++r) {
        float e = (pv[kt][r] > -1e29f) ? exp2f((pv[kt][r] - m) * 1.44269504f) : 0.f;
        pv[kt][r] = e;
        sum += e;
      }
    sum += __shfl_xor(sum, 16);
    sum += __shfl_xor(sum, 32);
    float rinv = 1.f / sum;

    int q = qt * 16 + lq;
    #pragma unroll
    for (int kt = 0; kt < 5; ++kt) {
      unsigned int u0 = (unsigned)f2bf(pv[kt][0] * rinv) | ((unsigned)f2bf(pv[kt][1] * rinv) << 16);
      unsigned int u1 = (unsigned)f2bf(pv[kt][2] * rinv) | ((unsigned)f2bf(pv[kt][3] * rinv) << 16);
      int byteo = q * (PS * 2) + kt * 32 + lg * 8;
      byteo ^= (q & 7) << 4;
      *(u32x2*)((char*)P + byteo) = (u32x2){u0, u1};
    }
    asm volatile("s_waitcnt lgkmcnt(0)" ::: "memory");

    bf16x8 bp[3];
    #pragma unroll
    for (int ks = 0; ks < 3; ++ks) {
      int byteo = q * (PS * 2) + ks * 64 + lg * 16;
      byteo ^= (q & 7) << 4;
      bp[ks] = *(const bf16x8*)((char*)P + byteo);
    }
    #pragma unroll
    for (int dt = 0; dt < 4; ++dt) {
      f32x4 o = (f32x4){0.f, 0.f, 0.f, 0.f};
      #pragma unroll
      for (int ks = 0; ks < 3; ++ks)
        o = __builtin_amdgcn_mfma_f32_16x16x32_bf16(vf[ks][dt], bp[ks], o, 0, 0, 0);
      if (q < 65) {
        unsigned int u0 = (unsigned)f2bf(o[0]) | ((unsigned)f2bf(o[1]) << 16);
        unsigned int u1 = (unsigned)f2bf(o[2]) | ((unsigned)f2bf(o[3]) << 16);
        *(u32x2*)(att + (size_t)(w * NT + q) * Cdim + h * 64 + dt * 16 + lg * 4) = (u32x2){u0, u1};
      }
    }
  }
}

// ---------- host ----------
extern "C" void kernel_launch(void* const* d_in, const int* in_sizes, int n_in,
                              void* d_out, int out_size, void* d_ws, size_t ws_size,
                              hipStream_t stream) {
  const float* x_img  = (const float*)d_in[0];
  const float* unseen = (const float*)d_in[2];
  const float* qkv_w  = (const float*)d_in[3];
  const float* qkv_b  = (const float*)d_in[4];
  const float* proj_w = (const float*)d_in[5];
  const float* proj_b = (const float*)d_in[6];

  char* ws = (char*)d_ws;
  size_t off = 0;
  auto alloc = [&](size_t bytes) { void* p = ws + off; off = (off + bytes + 255) & ~(size_t)255; return p; };
  unsigned short* xw  = (unsigned short*)alloc((size_t)ROWS * Cdim * 2);
  unsigned short* qkv = (unsigned short*)alloc((size_t)ROWS_PAD * C3 * 2);
  unsigned short* Vt  = (unsigned short*)alloc((size_t)12288 * 64 * TP * 2);
  unsigned short* wqb = (unsigned short*)alloc((size_t)C3 * Cdim * 2);
  unsigned short* wpb = (unsigned short*)alloc((size_t)Cdim * Cdim * 2);
  float* rope = (float*)alloc(64 * 16 * 2 * sizeof(float));

  hipMemsetAsync((float*)d_out + OUT_IMG, 0, 16 * Cdim * sizeof(float), stream);

  k_prep<<<512, 256, 0, stream>>>(qkv_w, proj_w, wqb, wpb, rope);
  k_xw<<<ROWS, 192, 0, stream>>>(x_img, unseen, xw);
  k_gemm<0, 9><<<260 * 9, 512, 0, stream>>>(xw, wqb, qkv_b, rope, qkv, nullptr);
  k_vt<<<12288, 256, 0, stream>>>(qkv, Vt);
  k_attn<<<dim3(12, 1024), 64, 0, stream>>>(qkv, Vt, xw);
  k_gemm<1, 3><<<260 * 3, 512, 0, stream>>>(xw, wpb, proj_b, nullptr, nullptr, (float*)d_out);
}